// Round 1
// baseline (339.113 us; speedup 1.0000x reference)
//
#include <hip/hip_runtime.h>
#include <hip/hip_bf16.h>

#define NB 2
#define NN 512
#define ND 256
#define NH 256
#define NH2 128

#define JT 128       // j-tile rows per block iteration
#define PADH 264     // padded row length (bf16 elems): 264*2=528B, 16B-aligned, 4-bank row shift

typedef __bf16 bf16x8 __attribute__((ext_vector_type(8)));
typedef __bf16 bf16x4 __attribute__((ext_vector_type(4)));
typedef float f32x4 __attribute__((ext_vector_type(4)));

// Kernel 1: per row bi in [0, B*N):
//   Lb[bi][h] = sum_d x[bi][d]*W1[d][h] + b1[h]
//   Rr[bi][h] = sum_d x[bi][d]*W1[D+d][h]
//   XW[bi][h] = sum_d x[bi][d]*Wg[d][h] + bg[h]   (bg folds since softmax rows sum to 1)
__global__ __launch_bounds__(256) void lr_kernel(
    const float* __restrict__ x, const float* __restrict__ W1,
    const float* __restrict__ b1, const float* __restrict__ Wg,
    const float* __restrict__ bg,
    float* __restrict__ Lb, float* __restrict__ Rr, float* __restrict__ XW) {
  __shared__ float xs[8][ND];
  const int r0 = blockIdx.x * 8;          // 128 blocks x 8 rows = 1024 rows
  const int tid = threadIdx.x;
  #pragma unroll
  for (int p = 0; p < 8; ++p) xs[p][tid] = x[(r0 + p) * ND + tid];
  __syncthreads();

  float accL[8], accR[8], accG[8];
  #pragma unroll
  for (int p = 0; p < 8; ++p) { accL[p] = 0.f; accR[p] = 0.f; accG[p] = 0.f; }
  const int h = tid;
  for (int d = 0; d < ND; ++d) {
    const float wl = W1[d * NH + h];
    const float wr = W1[(ND + d) * NH + h];
    const float wg = Wg[d * NH + h];
    #pragma unroll
    for (int p = 0; p < 8; ++p) {
      const float xv = xs[p][d];
      accL[p] = fmaf(xv, wl, accL[p]);
      accR[p] = fmaf(xv, wr, accR[p]);
      accG[p] = fmaf(xv, wg, accG[p]);
    }
  }
  const float bb1 = b1[h];
  const float bbg = bg[h];
  #pragma unroll
  for (int p = 0; p < 8; ++p) {
    Lb[(r0 + p) * NH + h] = accL[p] + bb1;
    Rr[(r0 + p) * NH + h] = accR[p];
    XW[(r0 + p) * NH + h] = accG[p] + bbg;
  }
}

// Kernel 2: one block per (b,i). Full fused pipeline:
//   edge weights row (MFMA GEMM) -> softmax -> out_row = p @ XW
__global__ __launch_bounds__(256) void edge_kernel(
    const float* __restrict__ x, const float* __restrict__ base_adj,
    const float* __restrict__ W2, const float* __restrict__ b2,
    const float* __restrict__ W3, const float* __restrict__ b3,
    const float* __restrict__ Lb, const float* __restrict__ Rr,
    const float* __restrict__ XW, float* __restrict__ out) {
  __shared__ __align__(16) __bf16 W2t[NH2][PADH];  // W2t[k][h] = W2[h][k], bf16
  __shared__ __align__(16) __bf16 Hs[JT][PADH];    // H tile, bf16
  __shared__ __align__(16) float Lbs[NH];
  __shared__ float b2s[NH2], W3s[NH2];
  __shared__ float ew[NN];       // edge row -> softmax probabilities
  __shared__ float red[2][JT];   // per-k-half partial pre-sigmoid sums
  __shared__ float sred[8];

  const int bi = blockIdx.x;          // 0..1023
  const int b = bi >> 9;
  const int i = bi & (NN - 1);
  const int tid = threadIdx.x;
  const int lane = tid & 63;
  const int w = tid >> 6;             // wave 0..3
  const int wy = w >> 1;              // j-half of tile (0/1)
  const int wx = w & 1;               // k-half (0/1)
  const int lr = lane & 15;
  const int lg = lane >> 4;

  // Stage W2 transposed as bf16, plus small vectors
  for (int idx = tid; idx < NH * NH2; idx += 256) {
    const int hh = idx >> 7;          // h
    const int kk = idx & (NH2 - 1);   // k
    W2t[kk][hh] = (__bf16)W2[idx];
  }
  Lbs[tid] = Lb[bi * NH + tid];
  if (tid < NH2) { b2s[tid] = b2[tid]; W3s[tid] = W3[tid]; }
  __syncthreads();

  const float* Rb = Rr + b * NN * NH;
  const float b3v = b3[0];

  for (int jt = 0; jt < NN; jt += JT) {
    // Build H tile: Hs[jj][h] = relu(Lbs[h] + R[jt+jj][h]) as bf16
    for (int q = tid; q < JT * 64; q += 256) {
      const int jj = q >> 6;
      const int h4 = (q & 63) << 2;
      const f32x4 rv = *(const f32x4*)(Rb + (jt + jj) * NH + h4);
      const f32x4 lv = *(const f32x4*)(Lbs + h4);
      bf16x4 hv;
      #pragma unroll
      for (int e = 0; e < 4; ++e) {
        float t = rv[e] + lv[e];
        hv[e] = (__bf16)(t > 0.f ? t : 0.f);
      }
      *(bf16x4*)(&Hs[jj][h4]) = hv;
    }
    __syncthreads();

    // MFMA: wave computes 64j x 64k of T = H @ W2
    f32x4 acc[4][4];
    #pragma unroll
    for (int ja = 0; ja < 4; ++ja)
      #pragma unroll
      for (int kb = 0; kb < 4; ++kb) acc[ja][kb] = (f32x4){0.f, 0.f, 0.f, 0.f};

    const __bf16* Hp = &Hs[0][0];
    const __bf16* Wp = &W2t[0][0];
    for (int ks = 0; ks < NH; ks += 32) {
      bf16x8 af[4], bfr[4];
      #pragma unroll
      for (int ja = 0; ja < 4; ++ja) {
        const int row = wy * 64 + ja * 16 + lr;
        af[ja] = *(const bf16x8*)(Hp + row * PADH + ks + lg * 8);
      }
      #pragma unroll
      for (int kb = 0; kb < 4; ++kb) {
        const int col = wx * 64 + kb * 16 + lr;
        bfr[kb] = *(const bf16x8*)(Wp + col * PADH + ks + lg * 8);
      }
      #pragma unroll
      for (int ja = 0; ja < 4; ++ja)
        #pragma unroll
        for (int kb = 0; kb < 4; ++kb)
          acc[ja][kb] = __builtin_amdgcn_mfma_f32_16x16x32_bf16(af[ja], bfr[kb], acc[ja][kb], 0, 0, 0);
    }

    // Epilogue: relu(T + b2) . W3, reduce over k
    #pragma unroll
    for (int ja = 0; ja < 4; ++ja) {
      #pragma unroll
      for (int r = 0; r < 4; ++r) {
        float s = 0.f;
        #pragma unroll
        for (int kb = 0; kb < 4; ++kb) {
          const int k = wx * 64 + kb * 16 + lr;   // C/D: col = lane&15
          float t = acc[ja][kb][r] + b2s[k];
          t = t > 0.f ? t : 0.f;
          s = fmaf(t, W3s[k], s);
        }
        s += __shfl_xor(s, 1, 16);
        s += __shfl_xor(s, 2, 16);
        s += __shfl_xor(s, 4, 16);
        s += __shfl_xor(s, 8, 16);
        if (lr == 0) red[wx][wy * 64 + ja * 16 + lg * 4 + r] = s;  // C/D: row = 4*(lane>>4)+reg
      }
    }
    __syncthreads();

    if (tid < JT) {
      const float v = red[0][tid] + red[1][tid] + b3v;
      const float sg = 1.f / (1.f + __expf(-v));
      const int j = jt + tid;
      ew[j] = base_adj[(b * NN + i) * NN + j] * sg + ((j == i) ? 1.f : 0.f);
    }
    __syncthreads();
  }

  // Softmax over ew[0..511]
  float v0 = ew[tid], v1 = ew[tid + 256];
  float m = fmaxf(v0, v1);
  #pragma unroll
  for (int off = 1; off < 64; off <<= 1) m = fmaxf(m, __shfl_xor(m, off, 64));
  if (lane == 0) sred[w] = m;
  __syncthreads();
  m = fmaxf(fmaxf(sred[0], sred[1]), fmaxf(sred[2], sred[3]));
  const float e0 = __expf(v0 - m), e1 = __expf(v1 - m);
  float ssum = e0 + e1;
  #pragma unroll
  for (int off = 1; off < 64; off <<= 1) ssum += __shfl_xor(ssum, off, 64);
  if (lane == 0) sred[4 + w] = ssum;
  __syncthreads();
  const float inv = 1.f / (sred[4] + sred[5] + sred[6] + sred[7]);
  ew[tid] = e0 * inv;
  ew[tid + 256] = e1 * inv;
  __syncthreads();

  // out_row[h] = sum_j p[j] * XW[b][j][h]   (bg already folded into XW)
  const float* XWb = XW + b * NN * NH;
  float o0 = 0.f, o1 = 0.f, o2 = 0.f, o3 = 0.f;
  for (int j = 0; j < NN; j += 4) {
    o0 = fmaf(ew[j + 0], XWb[(j + 0) * NH + tid], o0);
    o1 = fmaf(ew[j + 1], XWb[(j + 1) * NH + tid], o1);
    o2 = fmaf(ew[j + 2], XWb[(j + 2) * NH + tid], o2);
    o3 = fmaf(ew[j + 3], XWb[(j + 3) * NH + tid], o3);
  }
  out[bi * NH + tid] = (o0 + o1) + (o2 + o3);
}

extern "C" void kernel_launch(void* const* d_in, const int* in_sizes, int n_in,
                              void* d_out, int out_size, void* d_ws, size_t ws_size,
                              hipStream_t stream) {
  const float* x        = (const float*)d_in[0];
  const float* base_adj = (const float*)d_in[1];
  const float* W1       = (const float*)d_in[2];
  const float* b1       = (const float*)d_in[3];
  const float* W2       = (const float*)d_in[4];
  const float* b2       = (const float*)d_in[5];
  const float* W3       = (const float*)d_in[6];
  const float* b3       = (const float*)d_in[7];
  const float* Wg       = (const float*)d_in[8];
  const float* bg       = (const float*)d_in[9];

  float* Lb = (float*)d_ws;                 // [B*N, H]
  float* Rr = Lb + NB * NN * NH;            // [B*N, H]
  float* XW = Rr + NB * NN * NH;            // [B*N, H]  (x@Wg + bg)
  float* out = (float*)d_out;

  lr_kernel<<<(NB * NN) / 8, 256, 0, stream>>>(x, W1, b1, Wg, bg, Lb, Rr, XW);
  edge_kernel<<<NB * NN, 256, 0, stream>>>(x, base_adj, W2, b2, W3, b3, Lb, Rr, XW, out);
}

// Round 2
// 202.523 us; speedup vs baseline: 1.6744x; 1.6744x over previous
//
#include <hip/hip_runtime.h>
#include <hip/hip_bf16.h>

#define NB 2
#define NN 512
#define ND 256
#define NH 256
#define NH2 128

#define JT 128       // j-tile rows per block iteration
#define PADH 264     // padded row length (bf16 elems): 528B rows, 16B-shift per row

typedef __bf16 bf16x8 __attribute__((ext_vector_type(8)));
typedef float f32x4 __attribute__((ext_vector_type(4)));

// Fused prep: blocks [0,512) compute L/R/XW rows (2 rows per block);
// blocks [512,640) transpose-convert W2 -> bf16 W2b[k][h].
__global__ __launch_bounds__(256) void prep_kernel(
    const float* __restrict__ x, const float* __restrict__ W1,
    const float* __restrict__ b1, const float* __restrict__ Wg,
    const float* __restrict__ bg, const float* __restrict__ W2,
    float* __restrict__ Lb, float* __restrict__ Rr, float* __restrict__ XW,
    __bf16* __restrict__ W2b) {
  const int blk = blockIdx.x;
  const int tid = threadIdx.x;
  if (blk >= 512) {
    const int idx = (blk - 512) * 256 + tid;   // 0..32767
    const int k = idx >> 8;
    const int h = idx & 255;
    W2b[idx] = (__bf16)W2[h * NH2 + k];
    return;
  }
  __shared__ float xs[2][ND];
  const int r0 = blk * 2;
  xs[0][tid] = x[r0 * ND + tid];
  xs[1][tid] = x[(r0 + 1) * ND + tid];
  __syncthreads();

  float aL0 = 0.f, aL1 = 0.f, aR0 = 0.f, aR1 = 0.f, aG0 = 0.f, aG1 = 0.f;
  const int h = tid;
  for (int d = 0; d < ND; ++d) {
    const float wl = W1[d * NH + h];
    const float wr = W1[(ND + d) * NH + h];
    const float wg = Wg[d * NH + h];
    const float x0 = xs[0][d], x1 = xs[1][d];
    aL0 = fmaf(x0, wl, aL0); aL1 = fmaf(x1, wl, aL1);
    aR0 = fmaf(x0, wr, aR0); aR1 = fmaf(x1, wr, aR1);
    aG0 = fmaf(x0, wg, aG0); aG1 = fmaf(x1, wg, aG1);
  }
  const float bb1 = b1[h];
  const float bbg = bg[h];
  Lb[r0 * NH + h] = aL0 + bb1;       Lb[(r0 + 1) * NH + h] = aL1 + bb1;
  Rr[r0 * NH + h] = aR0;             Rr[(r0 + 1) * NH + h] = aR1;
  XW[r0 * NH + h] = aG0 + bbg;       XW[(r0 + 1) * NH + h] = aG1 + bbg;
}

// One block per (b,i). W2 fragments live in registers (loaded once from W2b).
// LDS ~71 KB -> 2 blocks/CU for phase overlap across independent blocks.
__global__ __launch_bounds__(256, 2) void edge_kernel(
    const float* __restrict__ base_adj,
    const float* __restrict__ b2, const float* __restrict__ W3,
    const float* __restrict__ b3, const float* __restrict__ Lb,
    const float* __restrict__ Rr, const float* __restrict__ XW,
    const __bf16* __restrict__ W2b, float* __restrict__ out) {
  __shared__ __align__(16) __bf16 Hs[JT][PADH];    // H tile, bf16
  __shared__ __align__(16) float Lbs[NH];
  __shared__ float b2s[NH2], W3s[NH2];
  __shared__ float ew[NN];       // edge row -> softmax probabilities
  __shared__ float red[2][JT];   // per-k-half partial pre-sigmoid sums
  __shared__ float sred[8];

  const int bi = blockIdx.x;          // 0..1023
  const int b = bi >> 9;
  const int i = bi & (NN - 1);
  const int tid = threadIdx.x;
  const int lane = tid & 63;
  const int w = tid >> 6;             // wave 0..3
  const int wy = w >> 1;              // j-half of tile (0/1)
  const int wx = w & 1;               // k-half (0/1)
  const int lr = lane & 15;
  const int lg = lane >> 4;

  // B fragments (W2) in registers: 8 K-steps x 4 col-blocks = 128 VGPRs
  bf16x8 bfr[8][4];
  #pragma unroll
  for (int ks8 = 0; ks8 < 8; ++ks8)
    #pragma unroll
    for (int kb = 0; kb < 4; ++kb) {
      const int col = wx * 64 + kb * 16 + lr;
      bfr[ks8][kb] = *(const bf16x8*)(W2b + col * NH + ks8 * 32 + lg * 8);
    }

  Lbs[tid] = Lb[bi * NH + tid];
  if (tid < NH2) { b2s[tid] = b2[tid]; W3s[tid] = W3[tid]; }
  __syncthreads();

  const float* Rb = Rr + b * NN * NH;
  const float b3v = b3[0];

  for (int jt = 0; jt < NN; jt += JT) {
    // Build H tile: Hs[jj][h] = relu(Lbs[h] + R[jt+jj][h]) as bf16 (8 elems/thread/iter)
    #pragma unroll
    for (int it = 0; it < 16; ++it) {
      const int q = it * 256 + tid;     // 4096 8-elem chunks
      const int jj = q >> 5;
      const int h8 = (q & 31) << 3;
      const f32x4 rv0 = *(const f32x4*)(Rb + (jt + jj) * NH + h8);
      const f32x4 rv1 = *(const f32x4*)(Rb + (jt + jj) * NH + h8 + 4);
      const f32x4 lv0 = *(const f32x4*)(Lbs + h8);
      const f32x4 lv1 = *(const f32x4*)(Lbs + h8 + 4);
      bf16x8 hv;
      #pragma unroll
      for (int e = 0; e < 4; ++e) {
        float t0 = rv0[e] + lv0[e];
        float t1 = rv1[e] + lv1[e];
        hv[e] = (__bf16)(t0 > 0.f ? t0 : 0.f);
        hv[e + 4] = (__bf16)(t1 > 0.f ? t1 : 0.f);
      }
      *(bf16x8*)(&Hs[jj][h8]) = hv;
    }
    __syncthreads();

    // MFMA: wave computes 64j x 64k of T = H @ W2 (B resident in regs)
    f32x4 acc[4][4];
    #pragma unroll
    for (int ja = 0; ja < 4; ++ja)
      #pragma unroll
      for (int kb = 0; kb < 4; ++kb) acc[ja][kb] = (f32x4){0.f, 0.f, 0.f, 0.f};

    const __bf16* Hp = &Hs[0][0];
    #pragma unroll
    for (int ks8 = 0; ks8 < 8; ++ks8) {
      bf16x8 af[4];
      #pragma unroll
      for (int ja = 0; ja < 4; ++ja) {
        const int row = wy * 64 + ja * 16 + lr;
        af[ja] = *(const bf16x8*)(Hp + row * PADH + ks8 * 32 + lg * 8);
      }
      #pragma unroll
      for (int ja = 0; ja < 4; ++ja)
        #pragma unroll
        for (int kb = 0; kb < 4; ++kb)
          acc[ja][kb] = __builtin_amdgcn_mfma_f32_16x16x32_bf16(af[ja], bfr[ks8][kb], acc[ja][kb], 0, 0, 0);
    }

    // Epilogue: relu(T + b2) . W3, reduce over k within each 16-lane group
    #pragma unroll
    for (int ja = 0; ja < 4; ++ja) {
      #pragma unroll
      for (int r = 0; r < 4; ++r) {
        float s = 0.f;
        #pragma unroll
        for (int kb = 0; kb < 4; ++kb) {
          const int k = wx * 64 + kb * 16 + lr;   // C/D: col = lane&15
          float t = acc[ja][kb][r] + b2s[k];
          t = t > 0.f ? t : 0.f;
          s = fmaf(t, W3s[k], s);
        }
        s += __shfl_xor(s, 1, 16);
        s += __shfl_xor(s, 2, 16);
        s += __shfl_xor(s, 4, 16);
        s += __shfl_xor(s, 8, 16);
        if (lr == 0) red[wx][wy * 64 + ja * 16 + lg * 4 + r] = s;  // row = 4*(lane>>4)+reg
      }
    }
    __syncthreads();

    if (tid < JT) {
      const float v = red[0][tid] + red[1][tid] + b3v;
      const float sg = 1.f / (1.f + __expf(-v));
      const int j = jt + tid;
      ew[j] = base_adj[(b * NN + i) * NN + j] * sg + ((j == i) ? 1.f : 0.f);
    }
    __syncthreads();
  }

  // Softmax over ew[0..511]
  float v0 = ew[tid], v1 = ew[tid + 256];
  float m = fmaxf(v0, v1);
  #pragma unroll
  for (int off = 1; off < 64; off <<= 1) m = fmaxf(m, __shfl_xor(m, off, 64));
  if (lane == 0) sred[w] = m;
  __syncthreads();
  m = fmaxf(fmaxf(sred[0], sred[1]), fmaxf(sred[2], sred[3]));
  const float e0 = __expf(v0 - m), e1 = __expf(v1 - m);
  float ssum = e0 + e1;
  #pragma unroll
  for (int off = 1; off < 64; off <<= 1) ssum += __shfl_xor(ssum, off, 64);
  if (lane == 0) sred[4 + w] = ssum;
  __syncthreads();
  const float inv = 1.f / (sred[4] + sred[5] + sred[6] + sred[7]);
  ew[tid] = e0 * inv;
  ew[tid + 256] = e1 * inv;
  __syncthreads();

  // out_row[h] = sum_j p[j] * XW[b][j][h]   (bg already folded into XW)
  const float* XWb = XW + b * NN * NH;
  float o0 = 0.f, o1 = 0.f, o2 = 0.f, o3 = 0.f;
  for (int j = 0; j < NN; j += 4) {
    o0 = fmaf(ew[j + 0], XWb[(j + 0) * NH + tid], o0);
    o1 = fmaf(ew[j + 1], XWb[(j + 1) * NH + tid], o1);
    o2 = fmaf(ew[j + 2], XWb[(j + 2) * NH + tid], o2);
    o3 = fmaf(ew[j + 3], XWb[(j + 3) * NH + tid], o3);
  }
  out[bi * NH + tid] = (o0 + o1) + (o2 + o3);
}

extern "C" void kernel_launch(void* const* d_in, const int* in_sizes, int n_in,
                              void* d_out, int out_size, void* d_ws, size_t ws_size,
                              hipStream_t stream) {
  const float* x        = (const float*)d_in[0];
  const float* base_adj = (const float*)d_in[1];
  const float* W1       = (const float*)d_in[2];
  const float* b1       = (const float*)d_in[3];
  const float* W2       = (const float*)d_in[4];
  const float* b2       = (const float*)d_in[5];
  const float* W3       = (const float*)d_in[6];
  const float* b3       = (const float*)d_in[7];
  const float* Wg       = (const float*)d_in[8];
  const float* bg       = (const float*)d_in[9];

  float* Lb = (float*)d_ws;                 // [B*N, H]
  float* Rr = Lb + NB * NN * NH;            // [B*N, H]
  float* XW = Rr + NB * NN * NH;            // [B*N, H]  (x@Wg + bg)
  __bf16* W2b = (__bf16*)(XW + NB * NN * NH);  // [H2, H] transposed bf16
  float* out = (float*)d_out;

  prep_kernel<<<512 + 128, 256, 0, stream>>>(x, W1, b1, Wg, bg, W2, Lb, Rr, XW, W2b);
  edge_kernel<<<NB * NN, 256, 0, stream>>>(base_adj, b2, W3, b3, Lb, Rr, XW, W2b, out);
}

// Round 3
// 163.266 us; speedup vs baseline: 2.0771x; 1.2405x over previous
//
#include <hip/hip_runtime.h>
#include <hip/hip_bf16.h>

#define NB 2
#define NN 512
#define ND 256
#define NH 256
#define NH2 128
#define JT 32        // j-tile rows per iteration (16 iters)

typedef __bf16 bf16x8 __attribute__((ext_vector_type(8)));
typedef __bf16 bf16x4 __attribute__((ext_vector_type(4)));
typedef float f32x4 __attribute__((ext_vector_type(4)));

__device__ __forceinline__ void gload_lds16(const void* g, void* l) {
  __builtin_amdgcn_global_load_lds((const __attribute__((address_space(1))) unsigned int*)g,
                                   (__attribute__((address_space(3))) unsigned int*)l, 16, 0, 0);
}
__device__ __forceinline__ float bflo(unsigned d) { return __uint_as_float(d << 16); }
__device__ __forceinline__ float bfhi(unsigned d) { return __uint_as_float(d & 0xffff0000u); }

// prep: blocks [0,512): L/R/XW rows (2 rows/block, d-split by 4 + LDS reduce);
//       blocks [512,640): W2 -> bf16 transposed W2b[k][h].
__global__ __launch_bounds__(256) void prep_kernel(
    const float* __restrict__ x, const float* __restrict__ W1,
    const float* __restrict__ b1, const float* __restrict__ Wg,
    const float* __restrict__ bg, const float* __restrict__ W2,
    float* __restrict__ Lb, __bf16* __restrict__ Rb16,
    __bf16* __restrict__ XWb16, __bf16* __restrict__ W2b) {
  const int blk = blockIdx.x;
  const int tid = threadIdx.x;
  if (blk >= 512) {
    const int idx = (blk - 512) * 256 + tid;   // 0..32767
    const int h = idx >> 7;
    const int k = idx & 127;
    W2b[k * NH + h] = (__bf16)W2[idx];         // coalesced read, scattered write
    return;
  }
  __shared__ float xs[2][ND];
  __shared__ __align__(16) f32x4 part[4 * 384];   // [dg][(r*3+m)*64+hq] : 24KB
  const int r0 = blk * 2;
  xs[0][tid] = x[r0 * ND + tid];
  xs[1][tid] = x[(r0 + 1) * ND + tid];
  __syncthreads();

  const int dg = tid >> 6;     // d-quarter
  const int hq = tid & 63;     // h-quad
  f32x4 acc[2][3];
  #pragma unroll
  for (int r = 0; r < 2; ++r)
    #pragma unroll
    for (int m = 0; m < 3; ++m) acc[r][m] = (f32x4){0.f, 0.f, 0.f, 0.f};

  const int d0 = dg * 64;
  for (int it = 0; it < 64; ++it) {
    const int d = d0 + it;
    const f32x4 wl = *(const f32x4*)(W1 + d * NH + hq * 4);
    const f32x4 wr = *(const f32x4*)(W1 + (ND + d) * NH + hq * 4);
    const f32x4 wg = *(const f32x4*)(Wg + d * NH + hq * 4);
    const float x0 = xs[0][d], x1 = xs[1][d];
    acc[0][0] += x0 * wl;  acc[0][1] += x0 * wr;  acc[0][2] += x0 * wg;
    acc[1][0] += x1 * wl;  acc[1][1] += x1 * wr;  acc[1][2] += x1 * wg;
  }
  #pragma unroll
  for (int r = 0; r < 2; ++r)
    #pragma unroll
    for (int m = 0; m < 3; ++m)
      part[dg * 384 + (r * 3 + m) * 64 + hq] = acc[r][m];
  __syncthreads();

  for (int s = tid; s < 384; s += 256) {
    f32x4 sum = part[s] + part[384 + s] + part[768 + s] + part[1152 + s];
    const int r = s / 192;
    const int rem = s - r * 192;
    const int m = rem >> 6;
    const int h = (rem & 63) * 4;
    const int row = r0 + r;
    if (m == 0) {
      const f32x4 bv = *(const f32x4*)(b1 + h);
      *(f32x4*)(Lb + row * NH + h) = sum + bv;
    } else if (m == 1) {
      bf16x4 o;
      #pragma unroll
      for (int e = 0; e < 4; ++e) o[e] = (__bf16)sum[e];
      *(bf16x4*)(Rb16 + row * NH + h) = o;
    } else {
      const f32x4 bv = *(const f32x4*)(bg + h);
      const f32x4 v = sum + bv;
      bf16x4 o;
      #pragma unroll
      for (int e = 0; e < 4; ++e) o[e] = (__bf16)v[e];
      *(bf16x4*)(XWb16 + row * NH + h) = o;
    }
  }
}

// edge: one block per (b,i). 4 blocks/CU. Async R staging via global_load_lds,
// Hs XOR-swizzled, W2 fragments in regs (64/wave), fused softmax + PV.
__global__ __launch_bounds__(256, 4) void edge_kernel(
    const float* __restrict__ base_adj,
    const float* __restrict__ b2, const float* __restrict__ W3,
    const float* __restrict__ b3, const float* __restrict__ Lb,
    const __bf16* __restrict__ Rb16, const __bf16* __restrict__ XWb16,
    const __bf16* __restrict__ W2b, float* __restrict__ out) {
  __shared__ __align__(16) __bf16 Rs[JT * NH];   // 16KB, linear (gload_lds dest)
  __shared__ __align__(16) __bf16 Hs[JT * NH];   // 16KB, chunk^(row&7) swizzle
  __shared__ __align__(16) float Lbs[NH];
  __shared__ float adjs[NN];    // raw base_adj row; reused as pv buffer at end
  __shared__ float ew[NN];
  __shared__ float red[4][JT];
  __shared__ float b2s[NH2], W3s[NH2];
  __shared__ float sred[8];

  const int bi = blockIdx.x;
  const int b = bi >> 9;
  const int i = bi & (NN - 1);
  const int tid = threadIdx.x;
  const int lane = tid & 63;
  const int w = tid >> 6;        // wave id; wx = w = k-quarter
  const int lr = lane & 15;
  const int lg = lane >> 4;

  const __bf16* Rbb = Rb16 + b * NN * NH;

  // prologue staging (jt=0): 4 issues/wave of 1KB
  {
    const int laneoff = (lane >> 5) * NH + (lane & 31) * 8;
    #pragma unroll
    for (int q = 0; q < 4; ++q) {
      const __bf16* src = Rbb + (w * 4 + q) * 2 * NH + laneoff;
      gload_lds16(src, (char*)Rs + (w * 4 + q) * 1024);
    }
  }
  // W2 fragments: wave w covers k in [w*32, w*32+32)
  bf16x8 bfr[8][2];
  #pragma unroll
  for (int ks8 = 0; ks8 < 8; ++ks8)
    #pragma unroll
    for (int kb = 0; kb < 2; ++kb) {
      const int k = w * 32 + kb * 16 + lr;
      bfr[ks8][kb] = *(const bf16x8*)(W2b + k * NH + ks8 * 32 + lg * 8);
    }
  Lbs[tid] = Lb[bi * NH + tid];
  adjs[tid] = base_adj[(b * NN + i) * NN + tid];
  adjs[tid + 256] = base_adj[(b * NN + i) * NN + tid + 256];
  if (tid < NH2) { b2s[tid] = b2[tid]; W3s[tid] = W3[tid]; }
  const float b3v = b3[0];
  asm volatile("s_waitcnt vmcnt(0)" ::: "memory");
  __syncthreads();

  // per-thread loop-invariant L slice: c = tid&31 every iteration
  const int cth = tid & 31;
  float l8[8];
  #pragma unroll
  for (int e = 0; e < 8; ++e) l8[e] = Lbs[cth * 8 + e];
  // build addresses: row = it*8 + (tid>>5), xor term constant
  const int rowth = tid >> 5;
  const unsigned rsAddr0 = tid * 16;                                   // bytes
  const unsigned hsAddr0 = rowth * 512 + ((cth ^ (rowth & 7)) << 4);   // bytes

  for (int jt = 0; jt < 16; ++jt) {
    // ---- build Hs = bf16(relu(L + R)) from Rs ----
    #pragma unroll
    for (int it = 0; it < 4; ++it) {
      const uint4 rv = *(const uint4*)((const char*)Rs + rsAddr0 + it * 4096);
      bf16x8 hb;
      #pragma unroll
      for (int e = 0; e < 4; ++e) {
        const unsigned d = ((const unsigned*)&rv)[e];
        float t0 = bflo(d) + l8[2 * e];
        float t1 = bfhi(d) + l8[2 * e + 1];
        t0 = t0 > 0.f ? t0 : 0.f;
        t1 = t1 > 0.f ? t1 : 0.f;
        hb[2 * e] = (__bf16)t0;
        hb[2 * e + 1] = (__bf16)t1;
      }
      *(bf16x8*)((char*)Hs + hsAddr0 + it * 4096) = hb;
    }
    __syncthreads();   // bar A: Hs ready, Rs consumed

    // ---- async stage next tile into Rs ----
    if (jt < 15) {
      const int laneoff = (lane >> 5) * NH + (lane & 31) * 8;
      const __bf16* base = Rbb + (jt + 1) * (JT * NH);
      #pragma unroll
      for (int q = 0; q < 4; ++q) {
        const __bf16* src = base + (w * 4 + q) * 2 * NH + laneoff;
        gload_lds16(src, (char*)Rs + (w * 4 + q) * 1024);
      }
    }

    // ---- MFMA: wave computes 32j x 32k ----
    f32x4 acc[2][2];
    #pragma unroll
    for (int ja = 0; ja < 2; ++ja)
      #pragma unroll
      for (int kb = 0; kb < 2; ++kb) acc[ja][kb] = (f32x4){0.f, 0.f, 0.f, 0.f};
    #pragma unroll
    for (int ks8 = 0; ks8 < 8; ++ks8) {
      bf16x8 af[2];
      #pragma unroll
      for (int ja = 0; ja < 2; ++ja) {
        const int row = ja * 16 + lr;
        const int c = (ks8 * 4 + lg) ^ (lr & 7);
        af[ja] = *(const bf16x8*)((const char*)Hs + row * 512 + (c << 4));
      }
      #pragma unroll
      for (int ja = 0; ja < 2; ++ja)
        #pragma unroll
        for (int kb = 0; kb < 2; ++kb)
          acc[ja][kb] = __builtin_amdgcn_mfma_f32_16x16x32_bf16(af[ja], bfr[ks8][kb], acc[ja][kb], 0, 0, 0);
    }

    // ---- epilogue: relu(T+b2).W3 partial sums ----
    #pragma unroll
    for (int ja = 0; ja < 2; ++ja) {
      #pragma unroll
      for (int r = 0; r < 4; ++r) {
        const int k0 = w * 32 + lr;
        float t0 = acc[ja][0][r] + b2s[k0];
        float t1 = acc[ja][1][r] + b2s[k0 + 16];
        t0 = t0 > 0.f ? t0 : 0.f;
        t1 = t1 > 0.f ? t1 : 0.f;
        float s = fmaf(t0, W3s[k0], t1 * W3s[k0 + 16]);
        s += __shfl_xor(s, 1, 16);
        s += __shfl_xor(s, 2, 16);
        s += __shfl_xor(s, 4, 16);
        s += __shfl_xor(s, 8, 16);
        if (lr == 0) red[w][ja * 16 + lg * 4 + r] = s;
      }
    }
    asm volatile("s_waitcnt vmcnt(0)" ::: "memory");
    __syncthreads();   // bar B: red ready, Hs consumed, Rs(jt+1) landed

    if (tid < JT) {
      const float v = red[0][tid] + red[1][tid] + red[2][tid] + red[3][tid] + b3v;
      const float sg = 1.f / (1.f + __expf(-v));
      const int j = jt * JT + tid;
      ew[j] = adjs[j] * sg + ((j == i) ? 1.f : 0.f);
    }
  }
  __syncthreads();

  // ---- softmax over ew[0..511] ----
  float v0 = ew[tid], v1 = ew[tid + 256];
  float m = fmaxf(v0, v1);
  #pragma unroll
  for (int off = 1; off < 64; off <<= 1) m = fmaxf(m, __shfl_xor(m, off, 64));
  if (lane == 0) sred[w] = m;
  __syncthreads();
  m = fmaxf(fmaxf(sred[0], sred[1]), fmaxf(sred[2], sred[3]));
  const float e0 = __expf(v0 - m), e1 = __expf(v1 - m);
  float ssum = e0 + e1;
  #pragma unroll
  for (int off = 1; off < 64; off <<= 1) ssum += __shfl_xor(ssum, off, 64);
  if (lane == 0) sred[4 + w] = ssum;
  __syncthreads();
  const float inv = 1.f / (sred[4] + sred[5] + sred[6] + sred[7]);
  ew[tid] = e0 * inv;
  ew[tid + 256] = e1 * inv;
  __syncthreads();

  // ---- PV: out_row = p @ XW (bf16, dword loads; pv reuses adjs) ----
  const int jg = tid >> 7;       // j-half
  const int h2 = tid & 127;      // h-pair
  const unsigned* Xp = (const unsigned*)(XWb16 + b * NN * NH) + jg * 256 * 128 + h2;
  float a0 = 0.f, a1 = 0.f, c0 = 0.f, c1 = 0.f;
  for (int jj = 0; jj < 256; jj += 2) {
    const int j0 = jg * 256 + jj;
    const unsigned d0 = Xp[jj * 128];
    const unsigned d1 = Xp[jj * 128 + 128];
    const float p0 = ew[j0], p1 = ew[j0 + 1];
    a0 = fmaf(p0, bflo(d0), a0);  a1 = fmaf(p0, bfhi(d0), a1);
    c0 = fmaf(p1, bflo(d1), c0);  c1 = fmaf(p1, bfhi(d1), c1);
  }
  float* pv = adjs;
  pv[jg * 256 + h2 * 2] = a0 + c0;
  pv[jg * 256 + h2 * 2 + 1] = a1 + c1;
  __syncthreads();
  out[bi * NH + tid] = pv[tid] + pv[256 + tid];
}

extern "C" void kernel_launch(void* const* d_in, const int* in_sizes, int n_in,
                              void* d_out, int out_size, void* d_ws, size_t ws_size,
                              hipStream_t stream) {
  const float* x        = (const float*)d_in[0];
  const float* base_adj = (const float*)d_in[1];
  const float* W1       = (const float*)d_in[2];
  const float* b1       = (const float*)d_in[3];
  const float* W2       = (const float*)d_in[4];
  const float* b2       = (const float*)d_in[5];
  const float* W3       = (const float*)d_in[6];
  const float* b3       = (const float*)d_in[7];
  const float* Wg       = (const float*)d_in[8];
  const float* bg       = (const float*)d_in[9];

  float*  Lb    = (float*)d_ws;                       // [1024,256] f32
  __bf16* Rb16  = (__bf16*)(Lb + NB * NN * NH);       // [1024,256] bf16
  __bf16* XWb16 = Rb16 + NB * NN * NH;                // [1024,256] bf16
  __bf16* W2b   = XWb16 + NB * NN * NH;               // [128,256]  bf16 (transposed)
  float* outp = (float*)d_out;

  prep_kernel<<<640, 256, 0, stream>>>(x, W1, b1, Wg, bg, W2, Lb, Rb16, XWb16, W2b);
  edge_kernel<<<NB * NN, 256, 0, stream>>>(base_adj, b2, W3, b3, Lb, Rb16, XWb16, W2b, outp);
}